// Round 3
// baseline (186.772 us; speedup 1.0000x reference)
//
#include <hip/hip_runtime.h>
#include <stdint.h>

// ---------------------------------------------------------------------------
// PlaneEmbeddingNetwork, round 9b (R9 + compile fix: cvt_pkrtz returns an
// __fp16 ext-vector; bit_cast it to v2h).
// R8: DPP quad_perm replaced all ds_bpermute -> 92us, VALUBusy 70%, busy time
// ~64us == known VALU exec floor. Remaining ~28us idle = VMEM chains:
//  (a) wave-start fids -> random 64B gather (~1400cy, paid by every wave,
//      nothing earlier to hide it), (b) 64 lane-varying fco_w loads in h-loop.
// R9 changes:
//  1. v_cvt_pkrtz (1 op) replaces RNE pack (3 ops) everywhere hot (~-64 ops).
//  2. h/fco restructure: fco_w/4 pre-packed as half2 in ws (region D);
//     quad-reduce h in f32 (exact), pack pooled pairs once, fco via fdot2
//     against ws table. 560 VALU + 32 VMEM vs 704 VALU + 64 VMEM per token.
//  3. 2 faces per quad (faces 2Q, 2Q+1 per lane): face-B's gather issues at
//     wave start and hides under face-A's ~2500cy compute; wave count halves,
//     halving the unhidden wave-start gather stall.
// absmax expected ~6-8e-3 (RTZ input rounding + f16 pooled), under the
// 1.23e-2 that passed previously. Pooling scale 0.25 folded into region D.
// ---------------------------------------------------------------------------

typedef float v2f __attribute__((ext_vector_type(2)));
typedef _Float16 v2h __attribute__((ext_vector_type(2)));

// DPP quad_perm ctrl: sel0 | sel1<<2 | sel2<<4 | sel3<<6 (out lane i <- sel[i])
#define DPP_ROT1 0x39  // [1,2,3,0]  lane t <- (t+1)&3
#define DPP_ROT2 0x4E  // [2,3,0,1]  lane t <- (t+2)&3  (== xor 2)
#define DPP_ROT3 0x93  // [3,0,1,2]  lane t <- (t+3)&3
#define DPP_XOR1 0xB1  // [1,0,3,2]  lane t <- t^1

static __device__ __forceinline__ v2f splat2(float x) { v2f r; r.x = x; r.y = x; return r; }
static __device__ __forceinline__ v2f fma2(v2f a, v2f b, v2f c) {
    return __builtin_elementwise_fma(a, b, c);
}

template<int CTRL>
static __device__ __forceinline__ float dppf(float x) {
    return __builtin_bit_cast(float,
        __builtin_amdgcn_mov_dpp(__builtin_bit_cast(int, x), CTRL, 0xF, 0xF, true));
}
template<int CTRL>
static __device__ __forceinline__ v2h dpph(v2h x) {
    return __builtin_bit_cast(v2h,
        __builtin_amdgcn_mov_dpp(__builtin_bit_cast(int, x), CTRL, 0xF, 0xF, true));
}
template<int CTRL>
static __device__ __forceinline__ v2f dpp2(v2f x) {
    v2f r; r.x = dppf<CTRL>(x.x); r.y = dppf<CTRL>(x.y); return r;
}

static __device__ __forceinline__ v2h pkh(float a, float b) {
    v2h r; r.x = (_Float16)a; r.y = (_Float16)b; return r;  // RNE casts (setup only)
}
static __device__ __forceinline__ v2h pkrtz(float a, float b) {
#if __has_builtin(__builtin_amdgcn_cvt_pkrtz)
    return __builtin_bit_cast(v2h, __builtin_amdgcn_cvt_pkrtz(a, b));
#else
    return pkh(a, b);
#endif
}
static __device__ __forceinline__ float fdot2(v2h a, v2h b, float c) {
#if __has_builtin(__builtin_amdgcn_fdot2)
    return __builtin_amdgcn_fdot2(a, b, c, false);
#else
    return fmaf((float)a.x, (float)b.x, fmaf((float)a.y, (float)b.y, c));
#endif
}
static __device__ __forceinline__ v2h ldh2(const uint32_t* p) {
    return __builtin_bit_cast(v2h, *p);
}
static __device__ __forceinline__ v2h ash(uint32_t u) {
    return __builtin_bit_cast(v2h, u);
}

// scores rotation r: a{h} += q_t . k_{(t+r)&3} via DPP-rotated k
template<int CTRL>
static __device__ __forceinline__ void score_rot(const v2h* qh, const v2h* kh,
                                                 float& r0, float& r1) {
    float a0 = 0.f, a1 = 0.f;
#pragma unroll
    for (int d = 0; d < 4; ++d) {
        a0 = fdot2(qh[d],     dpph<CTRL>(kh[d]),     a0);
        a1 = fdot2(qh[4 + d], dpph<CTRL>(kh[4 + d]), a1);
    }
    r0 = a0; r1 = a1;
}

// PV rotation r: o += p[r] * v_{(t+r)&3} via DPP-rotated v
template<int CTRL>
static __device__ __forceinline__ void pv_rot(const v2f* v, float pr0, float pr1,
                                              v2f* o) {
    const v2f ps0 = splat2(pr0), ps1 = splat2(pr1);
#pragma unroll
    for (int d = 0; d < 8; ++d) {
        const v2f vr = dpp2<CTRL>(v[d]);
        o[d] = fma2(d < 4 ? ps0 : ps1, vr, o[d]);
    }
}

// ---------------------------------------------------------------------------
// Setup kernel, 2 blocks. ws layout (4-byte units):
//  [0   .. 384): half2 wqkv[o*8+p]  = (w_in[2p][o], w_in[2p+1][o]), o in [0,48)
//  [384 .. 640): half2 w1t[c*8+p]   = (W1T[c][2p], W1T[c][2p+1]),   c in [0,32)
//                where W1T[c][d] = sum_e w_out[d*16+e] * fc_w[e*32+c]
//  [640 .. 672): float b1[c] = sum_e b_out[e]*fc_w[e*32+c] + fc_b[c]
//  [672 ..1184): half2 fco4[j*32+col] = (fco_w[2j][col], fco_w[2j+1][col])/4
// ---------------------------------------------------------------------------
__global__ void fold_w(const float* __restrict__ w_in,
                       const float* __restrict__ w_out,
                       const float* __restrict__ b_out,
                       const float* __restrict__ fc_w,
                       const float* __restrict__ fc_b,
                       const float* __restrict__ fco_w,
                       uint32_t* __restrict__ wsu) {
    const int tid = threadIdx.x;
    if (blockIdx.x == 1) {                 // region D: fco_w/4 packed half2
        if (tid < 512) {
            const int j = tid >> 5, col = tid & 31;
            wsu[672 + tid] = __builtin_bit_cast(uint32_t,
                pkh(fco_w[(2 * j) * 32 + col] * 0.25f,
                    fco_w[(2 * j + 1) * 32 + col] * 0.25f));
        }
        return;
    }
    if (tid < 384) {                       // region A: packed w_in
        const int o = tid >> 3, p = tid & 7;
        const v2h h = pkh(w_in[(2 * p) * 48 + o], w_in[(2 * p + 1) * 48 + o]);
        wsu[tid] = __builtin_bit_cast(uint32_t, h);
    } else if (tid < 640) {                // region B: packed W1T
        const int i = tid - 384, c = i >> 3, p = i & 7;
        float a0 = 0.f, a1 = 0.f;
#pragma unroll
        for (int e = 0; e < 16; ++e) {
            a0 = fmaf(w_out[(2 * p) * 16 + e],     fc_w[e * 32 + c], a0);
            a1 = fmaf(w_out[(2 * p + 1) * 16 + e], fc_w[e * 32 + c], a1);
        }
        wsu[tid] = __builtin_bit_cast(uint32_t, pkh(a0, a1));
    } else if (tid < 672) {                // region C: b1 (f32)
        const int c = tid - 640;
        float acc = fc_b[c];
#pragma unroll
        for (int e = 0; e < 16; ++e)
            acc = fmaf(b_out[e], fc_w[e * 32 + c], acc);
        reinterpret_cast<float*>(wsu)[640 + c] = acc;
    }
}

// Full per-token pipeline: qkv -> attn -> h -> quad-pool -> fco partial.
// xh: token embedding as 8 half2 d-pairs. op: output row base + t8.
static __device__ __forceinline__ void face_compute(
        const v2h* __restrict__ xh,
        const float* __restrict__ b_in,
        const uint32_t* __restrict__ wsu,
        const float* __restrict__ fco_b,
        float* __restrict__ op, int t8) {
    // ---- qkv projection via fdot2 (f32 accumulators, f16 inputs).
    //      k-bias dropped (softmax row-constant).
    float qa[16], ka[16], va[16];
#pragma unroll
    for (int o = 0; o < 16; ++o) {
        float aq = b_in[o], ak = 0.f, av = b_in[32 + o];
        const uint32_t* wq = wsu + o * 8;          // uniform -> s_load
        const uint32_t* wk = wsu + (16 + o) * 8;
        const uint32_t* wv = wsu + (32 + o) * 8;
#pragma unroll
        for (int p = 0; p < 8; ++p) {
            aq = fdot2(xh[p], ldh2(wq + p), aq);
            ak = fdot2(xh[p], ldh2(wk + p), ak);
            av = fdot2(xh[p], ldh2(wv + p), av);
        }
        qa[o] = aq; ka[o] = ak; va[o] = av;
    }

    v2h qh[8], kh[8];
    v2f v[8];
#pragma unroll
    for (int i = 0; i < 8; ++i) {
        qh[i] = pkrtz(qa[2 * i], qa[2 * i + 1]);
        kh[i] = pkrtz(ka[2 * i], ka[2 * i + 1]);
        v[i].x = va[2 * i]; v[i].y = va[2 * i + 1];
    }

    // ---- scores: p{h}[r] = q_t . k_{(t+r)%4}; k rotated by DPP quad_perm.
    float p0[4], p1[4];
    {
        float a0 = 0.f, a1 = 0.f;
#pragma unroll
        for (int d = 0; d < 4; ++d) {
            a0 = fdot2(qh[d], kh[d], a0);
            a1 = fdot2(qh[4 + d], kh[4 + d], a1);
        }
        p0[0] = a0; p1[0] = a1;
    }
    score_rot<DPP_ROT1>(qh, kh, p0[1], p1[1]);
    score_rot<DPP_ROT2>(qh, kh, p0[2], p1[2]);
    score_rot<DPP_ROT3>(qh, kh, p0[3], p1[3]);

    {   // softmax, no max-subtract (|score*scale| <~ 20 << exp2 range)
        const float C = 0.51006974841f;   // (1/sqrt(8)) * log2(e)
        float s0 = 0.f, s1 = 0.f;
#pragma unroll
        for (int j = 0; j < 4; ++j) {
            p0[j] = __builtin_amdgcn_exp2f(p0[j] * C); s0 += p0[j];
            p1[j] = __builtin_amdgcn_exp2f(p1[j] * C); s1 += p1[j];
        }
        const float r0 = __builtin_amdgcn_rcpf(s0);
        const float r1 = __builtin_amdgcn_rcpf(s1);
#pragma unroll
        for (int j = 0; j < 4; ++j) { p0[j] *= r0; p1[j] *= r1; }
    }

    // ---- PV (f32): o_t = sum_r p[r] * v_{(t+r)%4}, v rotated by DPP
    v2f o[8];
#pragma unroll
    for (int d = 0; d < 4; ++d) {
        o[d]     = splat2(p0[0]) * v[d];
        o[4 + d] = splat2(p1[0]) * v[4 + d];
    }
    pv_rot<DPP_ROT1>(v, p0[1], p1[1], o);
    pv_rot<DPP_ROT2>(v, p0[2], p1[2], o);
    pv_rot<DPP_ROT3>(v, p0[3], p1[3], o);

    v2h oh[8];
#pragma unroll
    for (int i = 0; i < 8; ++i) oh[i] = pkrtz(o[i].x, o[i].y);

    // ---- fused h + pool + fco:
    //  per c-pair j: h = relu(o . W1T + b1) via fdot2 (uniform s_load weights),
    //  quad-pool in f32 (exact), pack pooled pair once, accumulate 8 output
    //  cols via fdot2 against ws-resident fco_w/4 half2 table (region D).
    const uint32_t* w1t = wsu + 384;
    const float* b1 = reinterpret_cast<const float*>(wsu) + 640;
    const uint32_t* wd = wsu + 672 + t8;
    float acc[8];
    {
        const float4 ob0 = *reinterpret_cast<const float4*>(fco_b + t8);
        const float4 ob1 = *reinterpret_cast<const float4*>(fco_b + t8 + 4);
        acc[0] = ob0.x; acc[1] = ob0.y; acc[2] = ob0.z; acc[3] = ob0.w;
        acc[4] = ob1.x; acc[5] = ob1.y; acc[6] = ob1.z; acc[7] = ob1.w;
    }
#pragma unroll 4
    for (int j = 0; j < 16; ++j) {
        const uint32_t* wr0 = w1t + (2 * j) * 8;       // uniform -> s_load
        const uint32_t* wr1 = w1t + (2 * j + 1) * 8;
        float a0 = b1[2 * j], a1 = b1[2 * j + 1];
#pragma unroll
        for (int p = 0; p < 8; ++p) {
            a0 = fdot2(oh[p], ldh2(wr0 + p), a0);
            a1 = fdot2(oh[p], ldh2(wr1 + p), a1);
        }
        float h0 = fmaxf(a0, 0.f), h1 = fmaxf(a1, 0.f);
        float s0 = h0 + dppf<DPP_XOR1>(h0); s0 = s0 + dppf<DPP_ROT2>(s0);
        float s1 = h1 + dppf<DPP_XOR1>(h1); s1 = s1 + dppf<DPP_ROT2>(s1);
        const v2h ph = pkrtz(s0, s1);      // pooled pair; /4 folded in weights
        // 8 half2 cols of region D: two 16B lane-varying loads (L1-resident)
        const uint4 wa = *reinterpret_cast<const uint4*>(wd + j * 32);
        const uint4 wb = *reinterpret_cast<const uint4*>(wd + j * 32 + 4);
        acc[0] = fdot2(ph, ash(wa.x), acc[0]);
        acc[1] = fdot2(ph, ash(wa.y), acc[1]);
        acc[2] = fdot2(ph, ash(wa.z), acc[2]);
        acc[3] = fdot2(ph, ash(wa.w), acc[3]);
        acc[4] = fdot2(ph, ash(wb.x), acc[4]);
        acc[5] = fdot2(ph, ash(wb.y), acc[5]);
        acc[6] = fdot2(ph, ash(wb.z), acc[6]);
        acc[7] = fdot2(ph, ash(wb.w), acc[7]);
    }

    *reinterpret_cast<float4*>(op)     = make_float4(acc[0], acc[1], acc[2], acc[3]);
    *reinterpret_cast<float4*>(op + 4) = make_float4(acc[4], acc[5], acc[6], acc[7]);
}

__launch_bounds__(256, 4)
__global__ void face_net(const float* __restrict__ node,
                         const int*   __restrict__ fids,
                         const float* __restrict__ b_in,
                         const uint32_t* __restrict__ wsu,
                         const float* __restrict__ fco_b,
                         float* __restrict__ out, int F) {
    const int g = blockIdx.x * 256 + threadIdx.x;
    const int Q = g >> 2;                 // global quad id -> faces 2Q, 2Q+1
    const int fA = 2 * Q;
    if (fA >= F) return;                  // whole quads exit together
    const int t = g & 3;
    const int t8 = t * 8;
    const bool hasB = (fA + 1 < F);       // quad-uniform

    // ---- issue BOTH faces' gathers up front; face B's latency hides under
    //      face A's ~2500cy compute.
    const int nidA = fids[fA * 4 + t];
    const int nidB = hasB ? fids[fA * 4 + 4 + t] : nidA;
    const float* xpA = node + (size_t)nidA * 16;
    const float* xpB = node + (size_t)nidB * 16;
    const float4 a0 = *reinterpret_cast<const float4*>(xpA);
    const float4 a1 = *reinterpret_cast<const float4*>(xpA + 4);
    const float4 a2 = *reinterpret_cast<const float4*>(xpA + 8);
    const float4 a3 = *reinterpret_cast<const float4*>(xpA + 12);
    const float4 bv0 = *reinterpret_cast<const float4*>(xpB);
    const float4 bv1 = *reinterpret_cast<const float4*>(xpB + 4);
    const float4 bv2 = *reinterpret_cast<const float4*>(xpB + 8);
    const float4 bv3 = *reinterpret_cast<const float4*>(xpB + 12);

    v2h xhA[8];
    xhA[0] = pkrtz(a0.x, a0.y); xhA[1] = pkrtz(a0.z, a0.w);
    xhA[2] = pkrtz(a1.x, a1.y); xhA[3] = pkrtz(a1.z, a1.w);
    xhA[4] = pkrtz(a2.x, a2.y); xhA[5] = pkrtz(a2.z, a2.w);
    xhA[6] = pkrtz(a3.x, a3.y); xhA[7] = pkrtz(a3.z, a3.w);

    face_compute(xhA, b_in, wsu, fco_b, out + (size_t)fA * 32 + t8, t8);

    v2h xhB[8];
    xhB[0] = pkrtz(bv0.x, bv0.y); xhB[1] = pkrtz(bv0.z, bv0.w);
    xhB[2] = pkrtz(bv1.x, bv1.y); xhB[3] = pkrtz(bv1.z, bv1.w);
    xhB[4] = pkrtz(bv2.x, bv2.y); xhB[5] = pkrtz(bv2.z, bv2.w);
    xhB[6] = pkrtz(bv3.x, bv3.y); xhB[7] = pkrtz(bv3.z, bv3.w);

    if (hasB)
        face_compute(xhB, b_in, wsu, fco_b, out + (size_t)(fA + 1) * 32 + t8, t8);
}

extern "C" void kernel_launch(void* const* d_in, const int* in_sizes, int n_in,
                              void* d_out, int out_size, void* d_ws, size_t ws_size,
                              hipStream_t stream) {
    const float* node  = (const float*)d_in[0];
    const int*   fids  = (const int*)  d_in[1];
    const float* w_in  = (const float*)d_in[2];
    const float* b_in  = (const float*)d_in[3];
    const float* w_out = (const float*)d_in[4];
    const float* b_out = (const float*)d_in[5];
    const float* fc_w  = (const float*)d_in[6];
    const float* fc_b  = (const float*)d_in[7];
    const float* fco_w = (const float*)d_in[8];
    const float* fco_b = (const float*)d_in[9];
    float* out = (float*)d_out;
    uint32_t* wsu = (uint32_t*)d_ws;
    const int F = in_sizes[1] / 4;

    hipLaunchKernelGGL(fold_w, dim3(2), dim3(672), 0, stream,
                       w_in, w_out, b_out, fc_w, fc_b, fco_w, wsu);
    const int nQuads = (F + 1) / 2;
    const int threads = nQuads * 4;
    const int blocks = (threads + 255) / 256;
    hipLaunchKernelGGL(face_net, dim3(blocks), dim3(256), 0, stream,
                       node, fids, b_in, wsu, fco_b, out, F);
}

// Round 4
// 162.217 us; speedup vs baseline: 1.1514x; 1.1514x over previous
//
#include <hip/hip_runtime.h>
#include <stdint.h>

// ---------------------------------------------------------------------------
// PlaneEmbeddingNetwork, round 10.
// R9 post-mortem: 2-faces-per-quad REGRESSED (92->109us): occupancy 74->44%,
// VGPR 32->48, busy cycles +30% (interleaved double pipeline inflated the
// schedule). Revert to R8's shell (1 face/lane, 32 VGPR, occ 74%).
// Keep + add the VALU cuts (R8 busy time ~64us is the target):
//  1. v_cvt_pkrtz single-op f16 packs (vs 3-op RNE)        (~-60 ops/token)
//  2. h/fco restructure: fco_w/4 pre-packed half2 table in ws (region D);
//     quad-pool in f32, pack pooled pair once, fco accum via fdot2.
//     560 VALU + 32 VMEM vs 704 + 64 per token.
//  3. PV in packed f16: v as half2 (24 DPP movs vs 48), v_pk_mul/v_pk_fma
//     (32 packed vs 64 f32 ops), o lands packed for h-loop (skip 8 packs).
// Per-token VALU ~1400 -> ~1160 (-17%). Predict dur ~80us, VALUBusy ~68%,
// occupancy ~74%, absmax ~6-8e-3 (f16 PV partials; threshold >=1.23e-2).
// ---------------------------------------------------------------------------

typedef float v2f __attribute__((ext_vector_type(2)));
typedef _Float16 v2h __attribute__((ext_vector_type(2)));

// DPP quad_perm ctrl: sel0 | sel1<<2 | sel2<<4 | sel3<<6 (out lane i <- sel[i])
#define DPP_ROT1 0x39  // [1,2,3,0]  lane t <- (t+1)&3
#define DPP_ROT2 0x4E  // [2,3,0,1]  lane t <- (t+2)&3  (== xor 2)
#define DPP_ROT3 0x93  // [3,0,1,2]  lane t <- (t+3)&3
#define DPP_XOR1 0xB1  // [1,0,3,2]  lane t <- t^1

template<int CTRL>
static __device__ __forceinline__ float dppf(float x) {
    return __builtin_bit_cast(float,
        __builtin_amdgcn_mov_dpp(__builtin_bit_cast(int, x), CTRL, 0xF, 0xF, true));
}
template<int CTRL>
static __device__ __forceinline__ v2h dpph(v2h x) {
    return __builtin_bit_cast(v2h,
        __builtin_amdgcn_mov_dpp(__builtin_bit_cast(int, x), CTRL, 0xF, 0xF, true));
}

static __device__ __forceinline__ v2h pkh(float a, float b) {
    v2h r; r.x = (_Float16)a; r.y = (_Float16)b; return r;  // RNE casts (setup only)
}
static __device__ __forceinline__ v2h pkrtz(float a, float b) {
#if __has_builtin(__builtin_amdgcn_cvt_pkrtz)
    return __builtin_bit_cast(v2h, __builtin_amdgcn_cvt_pkrtz(a, b));
#else
    return pkh(a, b);
#endif
}
static __device__ __forceinline__ float fdot2(v2h a, v2h b, float c) {
#if __has_builtin(__builtin_amdgcn_fdot2)
    return __builtin_amdgcn_fdot2(a, b, c, false);
#else
    return fmaf((float)a.x, (float)b.x, fmaf((float)a.y, (float)b.y, c));
#endif
}
static __device__ __forceinline__ v2h fmah(v2h a, v2h b, v2h c) {
    return __builtin_elementwise_fma(a, b, c);   // v_pk_fma_f16
}
static __device__ __forceinline__ v2h ldh2(const uint32_t* p) {
    return __builtin_bit_cast(v2h, *p);
}
static __device__ __forceinline__ v2h ash(uint32_t u) {
    return __builtin_bit_cast(v2h, u);
}

// scores rotation r: a{h} += q_t . k_{(t+r)&3} via DPP-rotated k
template<int CTRL>
static __device__ __forceinline__ void score_rot(const v2h* qh, const v2h* kh,
                                                 float& r0, float& r1) {
    float a0 = 0.f, a1 = 0.f;
#pragma unroll
    for (int d = 0; d < 4; ++d) {
        a0 = fdot2(qh[d],     dpph<CTRL>(kh[d]),     a0);
        a1 = fdot2(qh[4 + d], dpph<CTRL>(kh[4 + d]), a1);
    }
    r0 = a0; r1 = a1;
}

// PV rotation r (packed f16): o[d] += p{h}[r] * v_{(t+r)&3}[d]
template<int CTRL>
static __device__ __forceinline__ void pv_rot(const v2h* vh, v2h ps0, v2h ps1,
                                              v2h* o) {
#pragma unroll
    for (int d = 0; d < 8; ++d) {
        const v2h vr = dpph<CTRL>(vh[d]);
        o[d] = fmah(d < 4 ? ps0 : ps1, vr, o[d]);
    }
}

// ---------------------------------------------------------------------------
// Setup kernel, 2 blocks. ws layout (4-byte units):
//  [0   .. 384): half2 wqkv[o*8+p]  = (w_in[2p][o], w_in[2p+1][o]), o in [0,48)
//  [384 .. 640): half2 w1t[c*8+p]   = (W1T[c][2p], W1T[c][2p+1]),   c in [0,32)
//                where W1T[c][d] = sum_e w_out[d*16+e] * fc_w[e*32+c]
//  [640 .. 672): float b1[c] = sum_e b_out[e]*fc_w[e*32+c] + fc_b[c]
//  [672 ..1184): half2 fco4[j*32+col] = (fco_w[2j][col], fco_w[2j+1][col])/4
// ---------------------------------------------------------------------------
__global__ void fold_w(const float* __restrict__ w_in,
                       const float* __restrict__ w_out,
                       const float* __restrict__ b_out,
                       const float* __restrict__ fc_w,
                       const float* __restrict__ fc_b,
                       const float* __restrict__ fco_w,
                       uint32_t* __restrict__ wsu) {
    const int tid = threadIdx.x;
    if (blockIdx.x == 1) {                 // region D: fco_w/4 packed half2
        if (tid < 512) {
            const int j = tid >> 5, col = tid & 31;
            wsu[672 + tid] = __builtin_bit_cast(uint32_t,
                pkh(fco_w[(2 * j) * 32 + col] * 0.25f,
                    fco_w[(2 * j + 1) * 32 + col] * 0.25f));
        }
        return;
    }
    if (tid < 384) {                       // region A: packed w_in
        const int o = tid >> 3, p = tid & 7;
        const v2h h = pkh(w_in[(2 * p) * 48 + o], w_in[(2 * p + 1) * 48 + o]);
        wsu[tid] = __builtin_bit_cast(uint32_t, h);
    } else if (tid < 640) {                // region B: packed W1T
        const int i = tid - 384, c = i >> 3, p = i & 7;
        float a0 = 0.f, a1 = 0.f;
#pragma unroll
        for (int e = 0; e < 16; ++e) {
            a0 = fmaf(w_out[(2 * p) * 16 + e],     fc_w[e * 32 + c], a0);
            a1 = fmaf(w_out[(2 * p + 1) * 16 + e], fc_w[e * 32 + c], a1);
        }
        wsu[tid] = __builtin_bit_cast(uint32_t, pkh(a0, a1));
    } else if (tid < 672) {                // region C: b1 (f32)
        const int c = tid - 640;
        float acc = fc_b[c];
#pragma unroll
        for (int e = 0; e < 16; ++e)
            acc = fmaf(b_out[e], fc_w[e * 32 + c], acc);
        reinterpret_cast<float*>(wsu)[640 + c] = acc;
    }
}

__launch_bounds__(256, 3)
__global__ void face_net(const float* __restrict__ node,
                         const int*   __restrict__ fids,
                         const float* __restrict__ b_in,
                         const uint32_t* __restrict__ wsu,
                         const float* __restrict__ fco_b,
                         float* __restrict__ out, int F) {
    const int g = blockIdx.x * 256 + threadIdx.x;
    const int f = g >> 2;
    if (f >= F) return;               // whole quads exit together (face-aligned)
    const int t = g & 3;
    const int t8 = t * 8;

    // ---- gather own token's embedding; convert to 8 half2 d-pairs
    const int nid = fids[g];
    const float* xp = node + (size_t)nid * 16;
    const float4 xv0 = *reinterpret_cast<const float4*>(xp);
    const float4 xv1 = *reinterpret_cast<const float4*>(xp + 4);
    const float4 xv2 = *reinterpret_cast<const float4*>(xp + 8);
    const float4 xv3 = *reinterpret_cast<const float4*>(xp + 12);
    v2h xh[8];
    xh[0] = pkrtz(xv0.x, xv0.y); xh[1] = pkrtz(xv0.z, xv0.w);
    xh[2] = pkrtz(xv1.x, xv1.y); xh[3] = pkrtz(xv1.z, xv1.w);
    xh[4] = pkrtz(xv2.x, xv2.y); xh[5] = pkrtz(xv2.z, xv2.w);
    xh[6] = pkrtz(xv3.x, xv3.y); xh[7] = pkrtz(xv3.z, xv3.w);

    // ---- qkv projection via fdot2 (f32 accumulators, f16 inputs).
    //      k-bias dropped (softmax row-constant).
    float qa[16], ka[16], va[16];
#pragma unroll
    for (int o = 0; o < 16; ++o) {
        float aq = b_in[o], ak = 0.f, av = b_in[32 + o];
        const uint32_t* wq = wsu + o * 8;          // uniform -> s_load
        const uint32_t* wk = wsu + (16 + o) * 8;
        const uint32_t* wv = wsu + (32 + o) * 8;
#pragma unroll
        for (int p = 0; p < 8; ++p) {
            aq = fdot2(xh[p], ldh2(wq + p), aq);
            ak = fdot2(xh[p], ldh2(wk + p), ak);
            av = fdot2(xh[p], ldh2(wv + p), av);
        }
        qa[o] = aq; ka[o] = ak; va[o] = av;
    }

    // q,k,v all as half2 pairs (v feeds packed-f16 PV).
    v2h qh[8], kh[8], vh[8];
#pragma unroll
    for (int i = 0; i < 8; ++i) {
        qh[i] = pkrtz(qa[2 * i], qa[2 * i + 1]);
        kh[i] = pkrtz(ka[2 * i], ka[2 * i + 1]);
        vh[i] = pkrtz(va[2 * i], va[2 * i + 1]);
    }

    // ---- scores: p{h}[r] = q_t . k_{(t+r)%4}; k rotated by DPP quad_perm.
    float p0[4], p1[4];
    {
        float a0 = 0.f, a1 = 0.f;
#pragma unroll
        for (int d = 0; d < 4; ++d) {
            a0 = fdot2(qh[d], kh[d], a0);
            a1 = fdot2(qh[4 + d], kh[4 + d], a1);
        }
        p0[0] = a0; p1[0] = a1;
    }
    score_rot<DPP_ROT1>(qh, kh, p0[1], p1[1]);
    score_rot<DPP_ROT2>(qh, kh, p0[2], p1[2]);
    score_rot<DPP_ROT3>(qh, kh, p0[3], p1[3]);

    {   // softmax, no max-subtract (|score*scale| <~ 20 << exp2 range)
        const float C = 0.51006974841f;   // (1/sqrt(8)) * log2(e)
        float s0 = 0.f, s1 = 0.f;
#pragma unroll
        for (int j = 0; j < 4; ++j) {
            p0[j] = __builtin_amdgcn_exp2f(p0[j] * C); s0 += p0[j];
            p1[j] = __builtin_amdgcn_exp2f(p1[j] * C); s1 += p1[j];
        }
        const float r0 = __builtin_amdgcn_rcpf(s0);
        const float r1 = __builtin_amdgcn_rcpf(s1);
#pragma unroll
        for (int j = 0; j < 4; ++j) { p0[j] *= r0; p1[j] *= r1; }
    }

    // packed (p,p) attention weights for f16 PV
    v2h ps0[4], ps1[4];
#pragma unroll
    for (int r = 0; r < 4; ++r) {
        ps0[r] = pkrtz(p0[r], p0[r]);
        ps1[r] = pkrtz(p1[r], p1[r]);
    }

    // ---- PV (packed f16): o_t = sum_r p[r] * v_{(t+r)%4}
    v2h o[8];
#pragma unroll
    for (int d = 0; d < 4; ++d) {
        o[d]     = ps0[0] * vh[d];        // v_pk_mul_f16
        o[4 + d] = ps1[0] * vh[4 + d];
    }
    pv_rot<DPP_ROT1>(vh, ps0[1], ps1[1], o);
    pv_rot<DPP_ROT2>(vh, ps0[2], ps1[2], o);
    pv_rot<DPP_ROT3>(vh, ps0[3], ps1[3], o);
    // o is already packed half2 for the h-loop dots

    // ---- fused h + pool + fco:
    //  per c-pair j: h = relu(o . W1T + b1) via fdot2 (uniform s_load weights),
    //  quad-pool in f32 (exact), pack pooled pair once, accumulate 8 output
    //  cols via fdot2 against ws-resident fco_w/4 half2 table (region D).
    const uint32_t* w1t = wsu + 384;
    const float* b1 = reinterpret_cast<const float*>(wsu) + 640;
    const uint32_t* wd = wsu + 672 + t8;
    float acc[8];
    {
        const float4 ob0 = *reinterpret_cast<const float4*>(fco_b + t8);
        const float4 ob1 = *reinterpret_cast<const float4*>(fco_b + t8 + 4);
        acc[0] = ob0.x; acc[1] = ob0.y; acc[2] = ob0.z; acc[3] = ob0.w;
        acc[4] = ob1.x; acc[5] = ob1.y; acc[6] = ob1.z; acc[7] = ob1.w;
    }
#pragma unroll 4
    for (int j = 0; j < 16; ++j) {
        const uint32_t* wr0 = w1t + (2 * j) * 8;       // uniform -> s_load
        const uint32_t* wr1 = w1t + (2 * j + 1) * 8;
        float a0 = b1[2 * j], a1 = b1[2 * j + 1];
#pragma unroll
        for (int p = 0; p < 8; ++p) {
            a0 = fdot2(o[p], ldh2(wr0 + p), a0);
            a1 = fdot2(o[p], ldh2(wr1 + p), a1);
        }
        float h0 = fmaxf(a0, 0.f), h1 = fmaxf(a1, 0.f);
        float s0 = h0 + dppf<DPP_XOR1>(h0); s0 = s0 + dppf<DPP_ROT2>(s0);
        float s1 = h1 + dppf<DPP_XOR1>(h1); s1 = s1 + dppf<DPP_ROT2>(s1);
        const v2h ph = pkrtz(s0, s1);      // pooled pair; /4 folded in weights
        // 8 half2 cols of region D: two 16B lane-varying loads (L1-resident)
        const uint4 wa = *reinterpret_cast<const uint4*>(wd + j * 32);
        const uint4 wb = *reinterpret_cast<const uint4*>(wd + j * 32 + 4);
        acc[0] = fdot2(ph, ash(wa.x), acc[0]);
        acc[1] = fdot2(ph, ash(wa.y), acc[1]);
        acc[2] = fdot2(ph, ash(wa.z), acc[2]);
        acc[3] = fdot2(ph, ash(wa.w), acc[3]);
        acc[4] = fdot2(ph, ash(wb.x), acc[4]);
        acc[5] = fdot2(ph, ash(wb.y), acc[5]);
        acc[6] = fdot2(ph, ash(wb.z), acc[6]);
        acc[7] = fdot2(ph, ash(wb.w), acc[7]);
    }

    // ---- store: 16B/lane, contiguous across the quad and wave
    float* op = out + (size_t)f * 32 + t8;
    *reinterpret_cast<float4*>(op)     = make_float4(acc[0], acc[1], acc[2], acc[3]);
    *reinterpret_cast<float4*>(op + 4) = make_float4(acc[4], acc[5], acc[6], acc[7]);
}

extern "C" void kernel_launch(void* const* d_in, const int* in_sizes, int n_in,
                              void* d_out, int out_size, void* d_ws, size_t ws_size,
                              hipStream_t stream) {
    const float* node  = (const float*)d_in[0];
    const int*   fids  = (const int*)  d_in[1];
    const float* w_in  = (const float*)d_in[2];
    const float* b_in  = (const float*)d_in[3];
    const float* w_out = (const float*)d_in[4];
    const float* b_out = (const float*)d_in[5];
    const float* fc_w  = (const float*)d_in[6];
    const float* fc_b  = (const float*)d_in[7];
    const float* fco_w = (const float*)d_in[8];
    const float* fco_b = (const float*)d_in[9];
    float* out = (float*)d_out;
    uint32_t* wsu = (uint32_t*)d_ws;
    const int F = in_sizes[1] / 4;

    hipLaunchKernelGGL(fold_w, dim3(2), dim3(672), 0, stream,
                       w_in, w_out, b_out, fc_w, fc_b, fco_w, wsu);
    const int threads = F * 4;
    const int blocks = (threads + 255) / 256;
    hipLaunchKernelGGL(face_net, dim3(blocks), dim3(256), 0, stream,
                       node, fids, b_in, wsu, fco_b, out, F);
}

// Round 5
// 134.888 us; speedup vs baseline: 1.3846x; 1.2026x over previous
//
#include <hip/hip_runtime.h>
#include <stdint.h>

// ---------------------------------------------------------------------------
// PlaneEmbeddingNetwork, round 11: MFMA for all GEMM-shaped blocks.
// R10: 82us, VALUBusy 77%, busy ~4970cyc/wave (~2480 VALU instrs) -- the
// irreducible dot work (qkv 384 + h 256 + fco 128 fdot2/token) IS the load.
// R11: per wave = 64 tokens = 16 faces:
//   qkv: [64,16]@[16,48] = 12x v_mfma_f32_16x16x16_f16 (4 row-tiles x q/k/v)
//   h:   [64,16]@[16,32] = 8 MFMA; C rows (lane>>4)*4+reg = one FACE ->
//        quad-pool is a free 4-reg relu+sum, no cross-lane ops
//   fco: [16,32]@[32,32] = 4 MFMA (2 K-tiles chained x 2 N-tiles)
// Attention (scores/softmax/PV) unchanged from R10 (DPP quad_perm + fdot2).
// Redistribution via wave-private LDS (no barriers, all C++ -> compiler
// tracks deps): qkv C-tiles pair-transposed (DPP xor1 exchange, even lanes
// write b128) into comp-pair-major [8][68] f16-pair rows; reads at stride-68
// dwords give qh/kh/vh directly. o staged token-major [64][10]; pooled f32
// [16][34]. Weights pre-packed into MFMA B-fragment order by fold_w.
// Predict: dur 82 -> ~45-55us, VALUBusy ~45%, MfmaUtil ~4%, VGPR ~64,
// absmax ~0.0039 (same numerics class: f16 in, f32 accum).
// ---------------------------------------------------------------------------

typedef float v2f __attribute__((ext_vector_type(2)));
typedef _Float16 v2h __attribute__((ext_vector_type(2)));
typedef __fp16 h4 __attribute__((ext_vector_type(4)));   // MFMA frag type
typedef float f32x4 __attribute__((ext_vector_type(4)));
typedef uint32_t u32x2 __attribute__((ext_vector_type(2)));
typedef uint32_t u32x4 __attribute__((ext_vector_type(4)));

// DPP quad_perm ctrl: sel0 | sel1<<2 | sel2<<4 | sel3<<6
#define DPP_ROT1 0x39  // lane t <- (t+1)&3
#define DPP_ROT2 0x4E  // lane t <- (t+2)&3
#define DPP_ROT3 0x93  // lane t <- (t+3)&3
#define DPP_XOR1 0xB1  // lane t <- t^1

template<int CTRL>
static __device__ __forceinline__ float dppf(float x) {
    return __builtin_bit_cast(float,
        __builtin_amdgcn_mov_dpp(__builtin_bit_cast(int, x), CTRL, 0xF, 0xF, true));
}
template<int CTRL>
static __device__ __forceinline__ v2h dpph(v2h x) {
    return __builtin_bit_cast(v2h,
        __builtin_amdgcn_mov_dpp(__builtin_bit_cast(int, x), CTRL, 0xF, 0xF, true));
}

static __device__ __forceinline__ v2h pkh(float a, float b) {
    v2h r; r.x = (_Float16)a; r.y = (_Float16)b; return r;  // RNE (setup only)
}
static __device__ __forceinline__ v2h pkrtz(float a, float b) {
#if __has_builtin(__builtin_amdgcn_cvt_pkrtz)
    return __builtin_bit_cast(v2h, __builtin_amdgcn_cvt_pkrtz(a, b));
#else
    return pkh(a, b);
#endif
}
static __device__ __forceinline__ float fdot2(v2h a, v2h b, float c) {
#if __has_builtin(__builtin_amdgcn_fdot2)
    return __builtin_amdgcn_fdot2(a, b, c, false);
#else
    return fmaf((float)a.x, (float)b.x, fmaf((float)a.y, (float)b.y, c));
#endif
}
static __device__ __forceinline__ v2h fmah(v2h a, v2h b, v2h c) {
    return __builtin_elementwise_fma(a, b, c);   // v_pk_fma_f16
}
static __device__ __forceinline__ v2h ash(uint32_t u) {
    return __builtin_bit_cast(v2h, u);
}
static __device__ __forceinline__ uint32_t bcu(v2h h) {
    return __builtin_bit_cast(uint32_t, h);
}
static __device__ __forceinline__ h4 mkh4(uint32_t lo, uint32_t hi) {
    u32x2 t; t.x = lo; t.y = hi; return __builtin_bit_cast(h4, t);
}
static __device__ __forceinline__ h4 ld2h(const uint32_t* p) {
    u32x2 t; t.x = p[0]; t.y = p[1]; return __builtin_bit_cast(h4, t);
}
static __device__ __forceinline__ f32x4 mfma16(h4 a, h4 b, f32x4 c) {
    return __builtin_amdgcn_mfma_f32_16x16x16f16(a, b, c, 0, 0, 0);
}

// scores rotation r: a{h} += q_t . k_{(t+r)&3} via DPP-rotated k
template<int CTRL>
static __device__ __forceinline__ void score_rot(const v2h* qh, const v2h* kh,
                                                 float& r0, float& r1) {
    float a0 = 0.f, a1 = 0.f;
#pragma unroll
    for (int d = 0; d < 4; ++d) {
        a0 = fdot2(qh[d],     dpph<CTRL>(kh[d]),     a0);
        a1 = fdot2(qh[4 + d], dpph<CTRL>(kh[4 + d]), a1);
    }
    r0 = a0; r1 = a1;
}
// PV rotation r (packed f16): o[d] += p{h}[r] * v_{(t+r)&3}[d]
template<int CTRL>
static __device__ __forceinline__ void pv_rot(const v2h* vh, v2h ps0, v2h ps1,
                                              v2h* o) {
#pragma unroll
    for (int d = 0; d < 8; ++d) {
        const v2h vr = dpph<CTRL>(vh[d]);
        o[d] = fmah(d < 4 ? ps0 : ps1, vr, o[d]);
    }
}

// Pair-transpose store of one qkv C-tile: lane holds (comp c0, tokens
// 16a+4*g2+r). DPP xor1 exchanges comp c0^1; even lanes pack (even,odd)
// f16 pairs and write 4 consecutive tokens as one b128 at comp-pair-major
// [8][68]-dword layout: J = (c0>>1)*68 + 16a + 4*g2 + r.
static __device__ __forceinline__ void xchg_store(uint32_t* S, int a, int c0,
                                                  int g2, f32x4 c) {
    const float p0 = dppf<DPP_XOR1>(c[0]);
    const float p1 = dppf<DPP_XOR1>(c[1]);
    const float p2 = dppf<DPP_XOR1>(c[2]);
    const float p3 = dppf<DPP_XOR1>(c[3]);
    if ((c0 & 1) == 0) {
        u32x4 w;
        w.x = bcu(pkrtz(c[0], p0));
        w.y = bcu(pkrtz(c[1], p1));
        w.z = bcu(pkrtz(c[2], p2));
        w.w = bcu(pkrtz(c[3], p3));
        *reinterpret_cast<u32x4*>(S + ((c0 >> 1) * 68 + 16 * a + 4 * g2)) = w;
    }
}

// ---------------------------------------------------------------------------
// fold_w: pre-pack all weights into MFMA B-fragment order (f16 pairs).
// ws layout (dwords):
//  [0   .. 384): Eqkv[T][l][d]: B[k=4*(l>>4)+2d+{0,1}][col=16T+(l&15)] of w_in
//  [384 .. 640): Eh[b][l][d]:   W1[k][16b+(l&15)], W1[d][c]=sum_e w_out[d][e]fc_w[e][c]
//  [640 .. 672): b1[c] = sum_e b_out[e]*fc_w[e*32+c] + fc_b[c]  (f32)
//  [672 ..1184): Efco[kt*2+n][l][d]: 0.25*fco_w[16kt+4*(l>>4)+2d+{0,1}][16n+(l&15)]
// ---------------------------------------------------------------------------
__global__ void fold_w(const float* __restrict__ w_in,
                       const float* __restrict__ w_out,
                       const float* __restrict__ b_out,
                       const float* __restrict__ fc_w,
                       const float* __restrict__ fc_b,
                       const float* __restrict__ fco_w,
                       uint32_t* __restrict__ wsu) {
    const int tid = threadIdx.x;
    if (blockIdx.x == 0) {
        if (tid < 384) {                   // Eqkv
            const int T = tid >> 7, r = tid & 127, l = r >> 1, d = r & 1;
            const int o = 16 * T + (l & 15), k0 = 4 * (l >> 4) + 2 * d;
            wsu[tid] = bcu(pkh(w_in[k0 * 48 + o], w_in[(k0 + 1) * 48 + o]));
        } else if (tid < 640) {            // Eh
            const int i = tid - 384, b = i >> 7, r = i & 127, l = r >> 1, d = r & 1;
            const int c = 16 * b + (l & 15), k0 = 4 * (l >> 4) + 2 * d;
            float a0 = 0.f, a1 = 0.f;
#pragma unroll
            for (int e = 0; e < 16; ++e) {
                a0 = fmaf(w_out[k0 * 16 + e],       fc_w[e * 32 + c], a0);
                a1 = fmaf(w_out[(k0 + 1) * 16 + e], fc_w[e * 32 + c], a1);
            }
            wsu[tid] = bcu(pkh(a0, a1));
        }
    } else {
        if (tid < 32) {                    // b1 (f32)
            float acc = fc_b[tid];
#pragma unroll
            for (int e = 0; e < 16; ++e)
                acc = fmaf(b_out[e], fc_w[e * 32 + tid], acc);
            reinterpret_cast<float*>(wsu)[640 + tid] = acc;
        } else if (tid < 544) {            // Efco (0.25 pooling folded in)
            const int i = tid - 32;
            const int kt = i >> 8, n = (i >> 7) & 1, r = i & 127, l = r >> 1, d = r & 1;
            const int col = 16 * n + (l & 15), k0 = 16 * kt + 4 * (l >> 4) + 2 * d;
            wsu[672 + i] = bcu(pkh(fco_w[k0 * 32 + col] * 0.25f,
                                   fco_w[(k0 + 1) * 32 + col] * 0.25f));
        }
    }
}

__launch_bounds__(256, 4)
__global__ void face_net(const float* __restrict__ node,
                         const int*   __restrict__ fids,
                         const float* __restrict__ b_in,
                         const uint32_t* __restrict__ wsu,
                         const float* __restrict__ fco_b,
                         float* __restrict__ out, int F) {
    const int l   = threadIdx.x & 63;
    const int wid = threadIdx.x >> 6;
    const int token_base = blockIdx.x * 256 + wid * 64;   // wave = 64 tokens
    if (token_base >= 4 * F) return;                      // whole waves exit
    const int c0 = l & 15, g2 = l >> 4;

    // wave-private LDS: S0 = 544 dw (pair-matrix / pooled), S1 = 640 dw (pair
    // matrix k / o-stage). No __syncthreads anywhere (intra-wave only).
    __shared__ __align__(16) uint8_t lds[4 * 4736];
    uint8_t* wl = lds + wid * 4736;
    uint32_t* S0 = reinterpret_cast<uint32_t*>(wl);           // 2176 B
    uint32_t* S1 = reinterpret_cast<uint32_t*>(wl + 2176);    // 2560 B

    // ---- gather A-fragments directly: tile a -> token 16a+c0, comps 4*g2..
    h4 A[4];
#pragma unroll
    for (int a = 0; a < 4; ++a) {
        const int tok = token_base + 16 * a + c0;
        const int nid = fids[tok];
        const float4 xv = *reinterpret_cast<const float4*>(
            node + (size_t)nid * 16 + g2 * 4);
        A[a] = mkh4(bcu(pkrtz(xv.x, xv.y)), bcu(pkrtz(xv.z, xv.w)));
    }

    // ---- qkv MFMAs (bias folded into C-init; k-bias dropped)
    const h4 Bq = ld2h(wsu + 0   + l * 2);
    const h4 Bk = ld2h(wsu + 128 + l * 2);
    const float bq = b_in[c0];
    {
        const f32x4 cq0 = {bq, bq, bq, bq};
        const f32x4 ck0 = {0.f, 0.f, 0.f, 0.f};
#pragma unroll
        for (int a = 0; a < 4; ++a) xchg_store(S0, a, c0, g2, mfma16(A[a], Bq, cq0));
#pragma unroll
        for (int a = 0; a < 4; ++a) xchg_store(S1, a, c0, g2, mfma16(A[a], Bk, ck0));
    }

    // ---- read back per-token q,k as half2 pairs (lane l = token l)
    v2h qh[8], kh[8];
#pragma unroll
    for (int u = 0; u < 4; ++u) {
        qh[2 * u]     = ash(S0[(2 * u) * 68 + l]);
        qh[2 * u + 1] = ash(S0[(2 * u + 1) * 68 + l]);
        kh[2 * u]     = ash(S1[(2 * u) * 68 + l]);
        kh[2 * u + 1] = ash(S1[(2 * u + 1) * 68 + l]);
    }

    // ---- scores: p{h}[r] = q_t . k_{(t+r)%4}; DPP quad rotations
    float p0[4], p1[4];
    {
        float a0 = 0.f, a1 = 0.f;
#pragma unroll
        for (int d = 0; d < 4; ++d) {
            a0 = fdot2(qh[d], kh[d], a0);
            a1 = fdot2(qh[4 + d], kh[4 + d], a1);
        }
        p0[0] = a0; p1[0] = a1;
    }
    score_rot<DPP_ROT1>(qh, kh, p0[1], p1[1]);
    score_rot<DPP_ROT2>(qh, kh, p0[2], p1[2]);
    score_rot<DPP_ROT3>(qh, kh, p0[3], p1[3]);

    {   // softmax, no max-subtract (|score*scale| small)
        const float C = 0.51006974841f;   // (1/sqrt(8)) * log2(e)
        float s0 = 0.f, s1 = 0.f;
#pragma unroll
        for (int j = 0; j < 4; ++j) {
            p0[j] = __builtin_amdgcn_exp2f(p0[j] * C); s0 += p0[j];
            p1[j] = __builtin_amdgcn_exp2f(p1[j] * C); s1 += p1[j];
        }
        const float r0 = __builtin_amdgcn_rcpf(s0);
        const float r1 = __builtin_amdgcn_rcpf(s1);
#pragma unroll
        for (int j = 0; j < 4; ++j) { p0[j] *= r0; p1[j] *= r1; }
    }

    // ---- v MFMAs (after q reads: S0 reused for v)
    const h4 Bv = ld2h(wsu + 256 + l * 2);
    const float bv = b_in[32 + c0];
    {
        const f32x4 cv0 = {bv, bv, bv, bv};
#pragma unroll
        for (int a = 0; a < 4; ++a) xchg_store(S0, a, c0, g2, mfma16(A[a], Bv, cv0));
    }
    v2h vh[8];
#pragma unroll
    for (int u = 0; u < 4; ++u) {
        vh[2 * u]     = ash(S0[(2 * u) * 68 + l]);
        vh[2 * u + 1] = ash(S0[(2 * u + 1) * 68 + l]);
    }

    // packed (p,p) attention weights; PV in packed f16
    v2h ps0[4], ps1[4];
#pragma unroll
    for (int r = 0; r < 4; ++r) {
        ps0[r] = pkrtz(p0[r], p0[r]);
        ps1[r] = pkrtz(p1[r], p1[r]);
    }
    v2h o[8];
#pragma unroll
    for (int d = 0; d < 4; ++d) {
        o[d]     = ps0[0] * vh[d];
        o[4 + d] = ps1[0] * vh[4 + d];
    }
    pv_rot<DPP_ROT1>(vh, ps0[1], ps1[1], o);
    pv_rot<DPP_ROT2>(vh, ps0[2], ps1[2], o);
    pv_rot<DPP_ROT3>(vh, ps0[3], ps1[3], o);

    // ---- stage o token-major [64][10] dw in S1 (k dead), read h A-frags
#pragma unroll
    for (int j = 0; j < 4; ++j) {
        u32x2 w; w.x = bcu(o[2 * j]); w.y = bcu(o[2 * j + 1]);
        *reinterpret_cast<u32x2*>(S1 + l * 10 + 2 * j) = w;
    }
    h4 Ao[4];
#pragma unroll
    for (int a = 0; a < 4; ++a) {
        const u32x2 t = *reinterpret_cast<const u32x2*>(
            S1 + (16 * a + c0) * 10 + 2 * g2);
        Ao[a] = __builtin_bit_cast(h4, t);
    }

    // ---- h MFMAs + free quad pooling (C rows = one face) -> P in S0
    const h4 Bh0 = ld2h(wsu + 384 + l * 2);
    const h4 Bh1 = ld2h(wsu + 384 + 128 + l * 2);
    const float* b1f = reinterpret_cast<const float*>(wsu) + 640;
    const float b10 = b1f[c0], b11 = b1f[16 + c0];
    float* Pf = reinterpret_cast<float*>(S0);   // [16][34] f32, v dead
    {
        const f32x4 ch0 = {b10, b10, b10, b10};
        const f32x4 ch1 = {b11, b11, b11, b11};
#pragma unroll
        for (int a = 0; a < 4; ++a) {
            const f32x4 h0 = mfma16(Ao[a], Bh0, ch0);
            const f32x4 h1 = mfma16(Ao[a], Bh1, ch1);
            const float s0 = fmaxf(h0[0], 0.f) + fmaxf(h0[1], 0.f)
                           + fmaxf(h0[2], 0.f) + fmaxf(h0[3], 0.f);
            const float s1 = fmaxf(h1[0], 0.f) + fmaxf(h1[1], 0.f)
                           + fmaxf(h1[2], 0.f) + fmaxf(h1[3], 0.f);
            Pf[(4 * a + g2) * 34 + c0]      = s0;   // unscaled; 0.25 in Efco
            Pf[(4 * a + g2) * 34 + 16 + c0] = s1;
        }
    }

    // ---- fco: A from P ([face l&15][cols 4g2.. / 16+4g2..]), 4 MFMA
    h4 Af[2];
#pragma unroll
    for (int kt = 0; kt < 2; ++kt) {
        const u32x2 pa = *reinterpret_cast<const u32x2*>(
            S0 + c0 * 34 + 16 * kt + 4 * g2);
        const u32x2 pb = *reinterpret_cast<const u32x2*>(
            S0 + c0 * 34 + 16 * kt + 4 * g2 + 2);
        const v2f fa = __builtin_bit_cast(v2f, pa);
        const v2f fb = __builtin_bit_cast(v2f, pb);
        Af[kt] = mkh4(bcu(pkrtz(fa.x, fa.y)), bcu(pkrtz(fb.x, fb.y)));
    }
    const h4 Bf00 = ld2h(wsu + 672 + 0 * 128 + l * 2);   // kt0,n0
    const h4 Bf01 = ld2h(wsu + 672 + 1 * 128 + l * 2);   // kt0,n1
    const h4 Bf10 = ld2h(wsu + 672 + 2 * 128 + l * 2);   // kt1,n0
    const h4 Bf11 = ld2h(wsu + 672 + 3 * 128 + l * 2);   // kt1,n1
    const float fb0 = fco_b[c0], fb1 = fco_b[16 + c0];
    f32x4 cf0 = {fb0, fb0, fb0, fb0};
    f32x4 cf1 = {fb1, fb1, fb1, fb1};
    cf0 = mfma16(Af[0], Bf00, cf0);
    cf0 = mfma16(Af[1], Bf10, cf0);
    cf1 = mfma16(Af[0], Bf01, cf1);
    cf1 = mfma16(Af[1], Bf11, cf1);

    // ---- store: C rows = faces 4*g2+r, cols c0 / 16+c0
    const int fbase = token_base >> 2;
    float* ob = out + (size_t)(fbase + 4 * g2) * 32 + c0;
#pragma unroll
    for (int r = 0; r < 4; ++r) {
        ob[r * 32]      = cf0[r];
        ob[r * 32 + 16] = cf1[r];
    }
}

extern "C" void kernel_launch(void* const* d_in, const int* in_sizes, int n_in,
                              void* d_out, int out_size, void* d_ws, size_t ws_size,
                              hipStream_t stream) {
    const float* node  = (const float*)d_in[0];
    const int*   fids  = (const int*)  d_in[1];
    const float* w_in  = (const float*)d_in[2];
    const float* b_in  = (const float*)d_in[3];
    const float* w_out = (const float*)d_in[4];
    const float* b_out = (const float*)d_in[5];
    const float* fc_w  = (const float*)d_in[6];
    const float* fc_b  = (const float*)d_in[7];
    const float* fco_w = (const float*)d_in[8];
    const float* fco_b = (const float*)d_in[9];
    float* out = (float*)d_out;
    uint32_t* wsu = (uint32_t*)d_ws;
    const int F = in_sizes[1] / 4;

    hipLaunchKernelGGL(fold_w, dim3(2), dim3(640), 0, stream,
                       w_in, w_out, b_out, fc_w, fc_b, fco_w, wsu);
    const int threads = F * 4;
    const int blocks = (threads + 255) / 256;
    hipLaunchKernelGGL(face_net, dim3(blocks), dim3(256), 0, stream,
                       node, fids, b_in, wsu, fco_b, out, F);
}